// Round 1
// 483.494 us; speedup vs baseline: 1.0299x; 1.0299x over previous
//
#include <hip/hip_runtime.h>

// S5 forward: GEMM1 (u @ Bbar^T) -> chunked complex scan -> GEMM2 (xs @ C'^T) + D*u
// B=8, L=4096, H=1024, P=512.  M = B*L = 32768, K = 1024, N = 1024 for both GEMMs.

#define Bsz 8
#define Lseq 4096
#define Hdim 1024
#define Pdim 512
#define NCHUNK 64
#define CHUNK 64
#define MROWS 32768

typedef __attribute__((ext_vector_type(8))) __bf16 bf16x8;
typedef __attribute__((ext_vector_type(4))) float f32x4;

__device__ __forceinline__ unsigned short f2bf(float f) {
  union { float f; unsigned u; } v; v.f = f;
  unsigned r = v.u + 0x7fffu + ((v.u >> 16) & 1u);
  return (unsigned short)(r >> 16);
}
__device__ __forceinline__ float bf2f(unsigned short s) {
  union { unsigned u; float f; } v; v.u = ((unsigned)s) << 16;
  return v.f;
}

__device__ __forceinline__ void gld_lds16(const void* g, void* l) {
  __builtin_amdgcn_global_load_lds(
      (const __attribute__((address_space(1))) unsigned int*)g,
      (__attribute__((address_space(3))) unsigned int*)l, 16, 0, 0);
}

// ---------------- setup: a = exp(Lambda*step), aS = a^CHUNK, g = (a-1)/Lambda ----------
__global__ void k_setup(const float* __restrict__ Lre_in, const float* __restrict__ Lim_in,
                        const float* __restrict__ log_step,
                        float2* __restrict__ a_arr, float2* __restrict__ aS_arr,
                        float2* __restrict__ g_arr) {
  int p = threadIdx.x;
  if (p >= Pdim) return;
  float lre = fminf(Lre_in[p], -1e-4f);
  float lim = Lim_in[p];
  float step = expf(log_step[p]);
  float zr = lre * step, zi = lim * step;
  float er = expf(zr);
  float ar = er * cosf(zi), ai = er * sinf(zi);
  a_arr[p] = make_float2(ar, ai);
  float erS = expf(zr * (float)CHUNK);
  aS_arr[p] = make_float2(erS * cosf(zi * (float)CHUNK), erS * sinf(zi * (float)CHUNK));
  float den = lre * lre + lim * lim;
  float nr = ar - 1.0f, ni = ai;
  g_arr[p] = make_float2((nr * lre + ni * lim) / den, (ni * lre - nr * lim) / den);
}

// ---------------- prep Bbar' (N=2P rows, K=H) bf16 ----------------
__global__ void k_prep_B(const float* __restrict__ Bin, const float2* __restrict__ g_arr,
                         unsigned short* __restrict__ Bbar2) {
  int idx = blockIdx.x * 256 + threadIdx.x;   // over P*H = 524288
  int p = idx >> 10;
  int h = idx & 1023;
  float B0 = Bin[2 * idx];      // B[p,h,0] : p*H*2 + h*2
  float B1 = Bin[2 * idx + 1];
  float2 g = g_arr[p];
  Bbar2[(size_t)p * Hdim + h]            = f2bf(g.x * B0 - g.y * B1);
  Bbar2[(size_t)(Pdim + p) * Hdim + h]   = f2bf(g.x * B1 + g.y * B0);
}

// ---------------- prep C' (N=H rows, K=2P) bf16 : [C_re | -C_im] ----------------
__global__ void k_prep_C(const float* __restrict__ Cin, unsigned short* __restrict__ C2m) {
  int idx = blockIdx.x * 256 + threadIdx.x;   // over H*P = 524288
  int h = idx >> 9;
  int p = idx & 511;
  float C0 = Cin[2 * idx];      // C[h,p,0] : h*P*2 + p*2
  float C1 = Cin[2 * idx + 1];
  C2m[(size_t)h * 1024 + p]        = f2bf(C0);
  C2m[(size_t)h * 1024 + 512 + p]  = f2bf(-C1);
}

// ---------------- u fp32 -> bf16 ----------------
__global__ void k_cvt_u(const float* __restrict__ u, unsigned short* __restrict__ ub) {
  size_t i = ((size_t)blockIdx.x * 256 + threadIdx.x) * 4;
  float4 v = *(const float4*)(u + i);
  ushort4 o;
  o.x = f2bf(v.x); o.y = f2bf(v.y); o.z = f2bf(v.z); o.w = f2bf(v.w);
  *(ushort4*)(ub + i) = o;
}

// ---------------- bf16 GEMM, B^T input, double-buffered LDS pipeline ----------------
// C[m,n] = sum_k A[m,k] * Bt[n,k];  M = 32768, N = 1024, K = 1024.
// Grid: 2048 1-D.  XCD-aware mapping: n-tile = wg & 7, m-tile = wg >> 3.
// The dispatcher round-robins blocks across the 8 XCDs (xcd = id % 8), so each XCD is
// pinned to ONE n-tile: its 256KB B-panel stays L2-resident, and all 8 XCDs sweep the
// same A m-tile near-simultaneously -> A fetched from HBM once, 7 L3 hits.
// LDS swizzle: slot (row r, chunk c) holds global k-chunk c ^ ((r>>1)&3); read back
// with c = quad ^ ((mrow>>1)&3) (invariant across mt/nt -> hoisted, no per-iter VALU).
// Pipeline: 1 barrier/iter; barrier's implicit vmcnt(0) drains loads issued LAST iter
// (full compute phase of latency hiding); prefetch issued right after the barrier.
// EPI 0: bf16 store via LDS transpose (256B runs).  EPI 1: fp32 = acc + D[n]*u[m,n].
template <int EPI>
__global__ __launch_bounds__(256, 4) void gemm_bt(const unsigned short* __restrict__ A,
                                                  const unsigned short* __restrict__ Bt,
                                                  void* __restrict__ Cout,
                                                  const float* __restrict__ uin,
                                                  const float* __restrict__ Dvec) {
  const int K = 1024;
  // bytes: buf b: As @ b*16384, Bs @ b*16384 + 8192. Epilogue reuses [0, 17408).
  __shared__ __align__(16) unsigned short sm[16384];
  char* smc = (char*)sm;

  int tid = threadIdx.x;
  int lane = tid & 63;
  int w = tid >> 6;          // wave 0..3
  int wr = w >> 1, wc = w & 1;
  int quad = lane >> 4;      // 0..3
  int mrow = lane & 15;

  int wg = blockIdx.x;
  size_t rowBase = (size_t)(wg >> 3) * 128;   // m-tile
  size_t colBase = (size_t)(wg & 7) * 128;    // n-tile (pinned per XCD)

  f32x4 acc[4][4];
#pragma unroll
  for (int i = 0; i < 4; i++)
#pragma unroll
    for (int j = 0; j < 4; j++) acc[i][j] = (f32x4){0.f, 0.f, 0.f, 0.f};

  // staging addresses (loop-invariant): slot idx = j*256 + tid; r = idx>>2; c = (idx&3)^((idx>>3)&3)
  int r0 = tid >> 2;
  int cst = (tid & 3) ^ ((tid >> 3) & 3);
  const unsigned short* pa0 = A + rowBase * K + (size_t)r0 * K + cst * 8;
  const unsigned short* pa1 = pa0 + (size_t)64 * K;
  const unsigned short* pb0 = Bt + colBase * K + (size_t)r0 * K + cst * 8;
  const unsigned short* pb1 = pb0 + (size_t)64 * K;
  int dA0 = w * 1024, dA1 = 4096 + w * 1024;
  int dB0 = 8192 + w * 1024, dB1 = 12288 + w * 1024;

  // LDS read bases (shorts), loop-invariant; frag mt/nt at +mt*512 shorts
  int cr = quad ^ ((mrow >> 1) & 3);
  int aOff = (wr * 64 + mrow) * 32 + cr * 8;
  int bOff = 4096 + (wc * 64 + mrow) * 32 + cr * 8;

  // prologue: stage tile 0 into buf 0
  gld_lds16(pa0, smc + dA0);
  gld_lds16(pa1, smc + dA1);
  gld_lds16(pb0, smc + dB0);
  gld_lds16(pb1, smc + dB1);

  for (int i = 0; i < 32; ++i) {
    __syncthreads();                       // drains vmcnt -> tile i resident; buf[i^1] free
    int cur = i & 1;
    if (i < 31) {
      int kb = (i + 1) * 32;
      int bb = (cur ^ 1) * 16384;
      gld_lds16(pa0 + kb, smc + bb + dA0);
      gld_lds16(pa1 + kb, smc + bb + dA1);
      gld_lds16(pb0 + kb, smc + bb + dB0);
      gld_lds16(pb1 + kb, smc + bb + dB1);
    }
    const unsigned short* Ab = sm + cur * 8192 + aOff;
    const unsigned short* Bb = sm + cur * 8192 + bOff;
    bf16x8 af[4], bfv[4];
#pragma unroll
    for (int mt = 0; mt < 4; mt++) af[mt] = *(const bf16x8*)(Ab + mt * 512);
#pragma unroll
    for (int nt = 0; nt < 4; nt++) bfv[nt] = *(const bf16x8*)(Bb + nt * 512);
#pragma unroll
    for (int mt = 0; mt < 4; mt++)
#pragma unroll
      for (int nt = 0; nt < 4; nt++)
        acc[mt][nt] = __builtin_amdgcn_mfma_f32_16x16x32_bf16(af[mt], bfv[nt], acc[mt][nt], 0, 0, 0);
  }

  // epilogue: C/D layout col = lane&15, row = quad*4 + r
  if (EPI == 0) {
    // LDS-transposed bf16 store: 2 passes of 64 rows through sm (stride 136)
    unsigned short* O = (unsigned short*)Cout;
    __syncthreads();
#pragma unroll
    for (int ph = 0; ph < 2; ph++) {
      if (wr == ph) {
#pragma unroll
        for (int mt = 0; mt < 4; mt++)
#pragma unroll
          for (int nt = 0; nt < 4; nt++)
#pragma unroll
            for (int r = 0; r < 4; r++) {
              int lr = mt * 16 + quad * 4 + r;
              int col = wc * 64 + nt * 16 + mrow;
              sm[lr * 136 + col] = f2bf(acc[mt][nt][r]);
            }
      }
      __syncthreads();
#pragma unroll
      for (int it = 0; it < 4; it++) {
        int cid = it * 256 + tid;           // 0..1023 over 64 rows x 16 chunks
        int lr = cid >> 4;
        int cc = cid & 15;
        uint4 v = *(const uint4*)(sm + lr * 136 + cc * 8);
        *(uint4*)(O + (rowBase + ph * 64 + lr) * 1024 + colBase + cc * 8) = v;
      }
      __syncthreads();
    }
  } else {
    float* O = (float*)Cout;
    size_t mBase = rowBase + wr * 64 + quad * 4;
    size_t nBase = colBase + wc * 64 + mrow;
#pragma unroll
    for (int mt = 0; mt < 4; mt++)
#pragma unroll
      for (int nt = 0; nt < 4; nt++) {
        size_t n = nBase + nt * 16;
        float dv = Dvec[n];
#pragma unroll
        for (int r = 0; r < 4; r++) {
          size_t m = mBase + mt * 16 + r;
          O[m * 1024 + n] = acc[mt][nt][r] + dv * uin[m * 1024 + n];
        }
      }
  }
}

// ---------------- scan phase 1: per-chunk aggregate T_c (ushort4 vectorized) ----------
// 2 chunks per 256-thread block; 128 threads/chunk, 4 p-states each (8B loads).
__global__ void k_scan1(const unsigned short* __restrict__ Bu, const float2* __restrict__ a_arr,
                        float* __restrict__ carryT) {
  int bc = blockIdx.x * 2 + (threadIdx.x >> 7);   // b*NCHUNK + c
  int t = threadIdx.x & 127;
  int p0 = t * 4;
  int b = bc >> 6, c = bc & 63;
  float2 a[4];
#pragma unroll
  for (int j = 0; j < 4; j++) a[j] = a_arr[p0 + j];
  const unsigned short* bu = Bu + ((size_t)b * Lseq + (size_t)c * CHUNK) * 1024;
  float tr[4] = {0.f, 0.f, 0.f, 0.f}, ti[4] = {0.f, 0.f, 0.f, 0.f};
#pragma unroll 4
  for (int l = 0; l < CHUNK; l++) {
    ushort4 vr = *(const ushort4*)(bu + (size_t)l * 1024 + p0);
    ushort4 vi = *(const ushort4*)(bu + (size_t)l * 1024 + 512 + p0);
    float br[4] = {bf2f(vr.x), bf2f(vr.y), bf2f(vr.z), bf2f(vr.w)};
    float bi[4] = {bf2f(vi.x), bf2f(vi.y), bf2f(vi.z), bf2f(vi.w)};
#pragma unroll
    for (int j = 0; j < 4; j++) {
      float nr = fmaf(a[j].x, tr[j], fmaf(-a[j].y, ti[j], br[j]));
      ti[j] = fmaf(a[j].x, ti[j], fmaf(a[j].y, tr[j], bi[j]));
      tr[j] = nr;
    }
  }
  *(float4*)(carryT + (size_t)bc * 1024 + p0) = make_float4(tr[0], tr[1], tr[2], tr[3]);
  *(float4*)(carryT + (size_t)bc * 1024 + 512 + p0) = make_float4(ti[0], ti[1], ti[2], ti[3]);
}

// ---------------- scan phase 2: scan chunk carries (coeff aS) ----------------
__global__ void k_scan2(const float* __restrict__ carryT, const float2* __restrict__ aS_arr,
                        float* __restrict__ prefix) {
  int b = blockIdx.x;
  int p = blockIdx.y * 256 + threadIdx.x;
  float2 s = aS_arr[p];
  float xr = 0.f, xi = 0.f;
#pragma unroll
  for (int c = 0; c < NCHUNK; c++) {
    size_t o = ((size_t)(b * NCHUNK + c)) * 1024 + p;
    prefix[o] = xr;
    prefix[o + 512] = xi;
    float tr = carryT[o], ti = carryT[o + 512];
    float nr = fmaf(s.x, xr, fmaf(-s.y, xi, tr));
    xi = fmaf(s.x, xi, fmaf(s.y, xr, ti));
    xr = nr;
  }
}

// ---------------- scan phase 3: replay chunk from carry-in, write xs bf16 (ushort4) ---
__global__ void k_scan3(const unsigned short* __restrict__ Bu, const float2* __restrict__ a_arr,
                        const float* __restrict__ prefix, unsigned short* __restrict__ xs) {
  int bc = blockIdx.x * 2 + (threadIdx.x >> 7);
  int t = threadIdx.x & 127;
  int p0 = t * 4;
  int b = bc >> 6, c = bc & 63;
  float2 a[4];
#pragma unroll
  for (int j = 0; j < 4; j++) a[j] = a_arr[p0 + j];
  size_t base = ((size_t)b * Lseq + (size_t)c * CHUNK) * 1024;
  size_t po = (size_t)bc * 1024 + p0;
  float4 xr4 = *(const float4*)(prefix + po);
  float4 xi4 = *(const float4*)(prefix + po + 512);
  float xr[4] = {xr4.x, xr4.y, xr4.z, xr4.w};
  float xi[4] = {xi4.x, xi4.y, xi4.z, xi4.w};
#pragma unroll 4
  for (int l = 0; l < CHUNK; l++) {
    ushort4 vr = *(const ushort4*)(Bu + base + (size_t)l * 1024 + p0);
    ushort4 vi = *(const ushort4*)(Bu + base + (size_t)l * 1024 + 512 + p0);
    float br[4] = {bf2f(vr.x), bf2f(vr.y), bf2f(vr.z), bf2f(vr.w)};
    float bi[4] = {bf2f(vi.x), bf2f(vi.y), bf2f(vi.z), bf2f(vi.w)};
    ushort4 orv, oiv;
#pragma unroll
    for (int j = 0; j < 4; j++) {
      float nr = fmaf(a[j].x, xr[j], fmaf(-a[j].y, xi[j], br[j]));
      xi[j] = fmaf(a[j].x, xi[j], fmaf(a[j].y, xr[j], bi[j]));
      xr[j] = nr;
    }
    orv.x = f2bf(xr[0]); orv.y = f2bf(xr[1]); orv.z = f2bf(xr[2]); orv.w = f2bf(xr[3]);
    oiv.x = f2bf(xi[0]); oiv.y = f2bf(xi[1]); oiv.z = f2bf(xi[2]); oiv.w = f2bf(xi[3]);
    *(ushort4*)(xs + base + (size_t)l * 1024 + p0) = orv;
    *(ushort4*)(xs + base + (size_t)l * 1024 + 512 + p0) = oiv;
  }
}

extern "C" void kernel_launch(void* const* d_in, const int* in_sizes, int n_in,
                              void* d_out, int out_size, void* d_ws, size_t ws_size,
                              hipStream_t stream) {
  const float* u     = (const float*)d_in[0];
  const float* Lre   = (const float*)d_in[1];
  const float* Lim   = (const float*)d_in[2];
  const float* Bin   = (const float*)d_in[3];
  const float* Cin   = (const float*)d_in[4];
  const float* Dvec  = (const float*)d_in[5];
  const float* lstep = (const float*)d_in[6];

  char* ws = (char*)d_ws;
  // ws layout (~75.5 MB):
  unsigned short* ubf_xs = (unsigned short*)(ws);                    // 67,108,864 B (u_bf16, later reused as xs)
  unsigned short* Bbar2  = (unsigned short*)(ws + 67108864);         // 2 MB
  unsigned short* C2m    = (unsigned short*)(ws + 69206016);         // 2 MB
  float*          carryT = (float*)(ws + 71303168);                  // 2 MB
  float*          prefix = (float*)(ws + 73400320);                  // 2 MB
  float2*         a_arr  = (float2*)(ws + 75497472);
  float2*         aS_arr = (float2*)(ws + 75501568);
  float2*         g_arr  = (float2*)(ws + 75505664);

  // Bu lives in d_out (bf16, 67MB of the 134MB out buffer); dead before GEMM2 writes out.
  unsigned short* Bu = (unsigned short*)d_out;

  k_setup<<<1, 512, 0, stream>>>(Lre, Lim, lstep, a_arr, aS_arr, g_arr);
  k_prep_B<<<2048, 256, 0, stream>>>(Bin, g_arr, Bbar2);
  k_prep_C<<<2048, 256, 0, stream>>>(Cin, C2m);
  k_cvt_u<<<32768, 256, 0, stream>>>(u, ubf_xs);

  gemm_bt<0><<<2048, 256, 0, stream>>>(ubf_xs, Bbar2, (void*)Bu, nullptr, nullptr);

  k_scan1<<<256, 256, 0, stream>>>(Bu, a_arr, carryT);
  k_scan2<<<dim3(Bsz, 2), 256, 0, stream>>>(carryT, aS_arr, prefix);
  k_scan3<<<256, 256, 0, stream>>>(Bu, a_arr, prefix, ubf_xs);

  gemm_bt<1><<<2048, 256, 0, stream>>>(ubf_xs, C2m, d_out, u, Dvec);
}